// Round 2
// baseline (8329.382 us; speedup 1.0000x reference)
//
#include <hip/hip_runtime.h>
#include <hip/hip_bf16.h>
#include <stdint.h>

// RNNPB: B=30 independent recurrent sequences, T=8192 sequential steps.
// Folded recurrence:  z_{t+1} = M @ h_t + m0,  M = W1c@W2c [240x240], m0 = W1c@b2c
//                     h_t     = relu(dproj_t + cb + z_t)      (z_0 = 0)
//                     out_t   = W2d @ h_t + b2d   (W2d appended as rows 240..245 of M)
// One workgroup (256 thr) per batch element; M persistent in VGPRs (256 f32/thread).
// Input/output dtype (fp32 vs bf16) is UNKNOWN at build time -> detected on device.

#define T_STEPS 8192
#define B_NUM   30
#define HID     240
#define CTX     180
#define AUG_ROWS 248                       // 240 z-rows + 6 out rows + 2 pad
#define M_ELEMS (AUG_ROWS*HID)             // 59520
#define M0_OFF  M_ELEMS                    // m0[240]
#define FLAG_OFF (M_ELEMS + HID)           // int flag: 1 = fp32 inputs/outputs
#define SCRATCH_FLOATS (M_ELEMS + HID + 16)

typedef __hip_bfloat16 bf16;

__device__ __forceinline__ float ldin(const void* p, int i, bool f32) {
    return f32 ? ((const float*)p)[i]
               : __bfloat162float(((const bf16*)p)[i]);
}

// One wave probes data[]'s bit patterns. fp32 arrays: low half-words are random
// mantissa bits -> as bf16, exponent >= 0x8E (|v|>=2^15) with p~0.45/word, or
// exactly 0 everywhere if values are bf16-grid. Genuine bf16 arrays: low halves
// are real N(0,1) samples -> small exponents, almost never all zero.
__global__ __launch_bounds__(64) void detect_dtype(const void* data, int* flag) {
    unsigned int w  = ((const unsigned int*)data)[threadIdx.x];
    unsigned int lo = w & 0xFFFFu;
    unsigned int ex = (lo >> 7) & 0xFFu;
    unsigned long long huge = __ballot(ex >= 0x8Eu);
    unsigned long long zero = __ballot(lo == 0u);
    if (threadIdx.x == 0) *flag = (huge != 0ull || zero == ~0ull) ? 1 : 0;
}

// ---------------- setup kernel: build augmented M + m0 in scratch ----------------
__global__ __launch_bounds__(256) void build_M(
    const void* __restrict__ W1c, const void* __restrict__ W2c,
    const void* __restrict__ b2c, const void* __restrict__ W2d,
    float* __restrict__ Mbuf, const int* __restrict__ flagp)
{
    const bool f32 = (*flagp != 0);
    int tid = blockIdx.x*256 + threadIdx.x;
    if (tid < M_ELEMS) {
        int j = tid / HID, k = tid - j*HID;
        float v;
        if (j < HID) {                       // M[j][k] = sum_c W1c[j,c]*W2c[c,k]
            float acc = 0.f;
            for (int c = 0; c < CTX; ++c)
                acc = fmaf(ldin(W1c, j*CTX+c, f32), ldin(W2c, c*HID+k, f32), acc);
            v = acc;
        } else if (j < HID+6) {              // out rows = W2d
            v = ldin(W2d, (j-HID)*HID + k, f32);
        } else v = 0.f;                      // pad rows
        Mbuf[tid] = v;
    } else if (tid < M_ELEMS + HID) {        // m0[j] = sum_c W1c[j,c]*b2c[c]
        int jj = tid - M_ELEMS;
        float acc = 0.f;
        for (int c = 0; c < CTX; ++c)
            acc = fmaf(ldin(W1c, jj*CTX+c, f32), ldin(b2c, c, f32), acc);
        Mbuf[tid] = acc;
    }
}

// DPP add helper: v += v_from(lane per CTRL), VALU pipe (no LDS traffic)
template<int CTRL>
__device__ __forceinline__ float dpp_add(float v) {
    int x = __builtin_bit_cast(int, v);
    int y = __builtin_amdgcn_update_dpp(0, x, CTRL, 0xF, 0xF, true);
    return v + __builtin_bit_cast(float, y);
}

// ---------------- persistent recurrent kernel: 1 workgroup per batch elem ----------------
__global__ __launch_bounds__(256, 1) void rnn_run(
    const void* __restrict__ data,   // [30][6][8192]
    const void* __restrict__ W1d,    // [240][6]
    const void* __restrict__ b1d,    // [240]
    const void* __restrict__ W1p,    // [240][2]
    const void* __restrict__ b1p,    // [240]
    const void* __restrict__ b1c,    // [240]
    const void* __restrict__ b2d,    // [6]
    const void* __restrict__ pb,     // [30][2]
    const float* __restrict__ Mbuf,  // [248][240] + m0[240] + flag
    const int* __restrict__ flagp,
    void* __restrict__ out)          // [30][8192][6]
{
    const bool f32 = (*flagp != 0);
    const int tid = threadIdx.x;
    const int b   = blockIdx.x;
    const int cg  = tid & 7;         // lane-in-group == col-group == owned-row offset
    const int rg  = tid >> 3;        // row group 0..31 (31 = dummy)
    const int j   = rg*8 + cg;       // owned row (z-row if <240, out-row 240..245)

    // LDS: h double-buffer (8 chunks of 32, stride 36 kills bank conflicts),
    //      data window double-buffer, out staging double-buffer (fp32).
    __shared__ __align__(16) float h2[2][8*36];      // 2304 B
    __shared__ __align__(16) float dbuf2[2][32][6];  // 1536 B
    __shared__ __align__(16) float obufF[2][32][6];  // 1536 B

    // ---- load persistent M fragment: rows rg*8+r, cols cg*32+i
    // (rows clamped to pad row 247; cols >=240 read next-row garbage, but the
    //  matching h slots are hard-zero forever, so garbage*0 = 0 and all finite)
    float Mreg[8][32];
    #pragma unroll
    for (int r = 0; r < 8; ++r) {
        int row = rg*8 + r; if (row > AUG_ROWS-1) row = AUG_ROWS-1;
        const float* src = Mbuf + row*HID + cg*32;
        #pragma unroll
        for (int i = 0; i < 32; ++i) Mreg[r][i] = src[i];
    }

    // ---- per-lane constants
    float w1dr[6] = {0,0,0,0,0,0};
    float cb = 0.f, zc = 0.f, b2dr = 0.f;
    const bool zrow = (j < HID);
    const bool outlane = (rg == 30 && cg < 6);
    if (zrow) {
        #pragma unroll
        for (int d = 0; d < 6; ++d) w1dr[d] = ldin(W1d, j*6+d, f32);
        float p0 = ldin(pb, b*2+0, f32);
        float p1 = ldin(pb, b*2+1, f32);
        cb = ldin(b1d, j, f32) + ldin(b1c, j, f32) + ldin(b1p, j, f32)
           + p0*ldin(W1p, j*2+0, f32) + p1*ldin(W1p, j*2+1, f32);
        zc = cb + Mbuf[M0_OFF + j];          // cb + m0 (used for t>=1)
    } else if (outlane) {
        b2dr = ldin(b2d, cg, f32);
    }
    const int hidx = (j>>5)*36 + (j&31);

    // ---- zero h buffers (pads must stay 0 forever)
    for (int i = tid; i < 2*8*36; i += 256) (&h2[0][0])[i] = 0.f;

    const size_t dbase = (size_t)b*6*T_STEPS;

    // ---- fill data window W_0 = d[0..32)
    if (tid < 96) {
        int d = tid >> 4, c = tid & 15;
        float v0, v1;
        if (f32) {
            float2 vv = *(const float2*)((const float*)data + dbase + (size_t)d*T_STEPS + c*2);
            v0 = vv.x; v1 = vv.y;
        } else {
            unsigned int w = *(const unsigned int*)((const bf16*)data + dbase + (size_t)d*T_STEPS + c*2);
            v0 = __bfloat162float(__builtin_bit_cast(bf16, (unsigned short)(w & 0xFFFFu)));
            v1 = __bfloat162float(__builtin_bit_cast(bf16, (unsigned short)(w >> 16)));
        }
        dbuf2[0][c*2+0][d] = v0;
        dbuf2[0][c*2+1][d] = v1;
    }
    __syncthreads();

    // ---- h_0 = relu(dproj_0 + cb)   (z_0 = 0, no m0)
    if (zrow) {
        float pre = cb;
        #pragma unroll
        for (int d = 0; d < 6; ++d) pre = fmaf(w1dr[d], dbuf2[0][0][d], pre);
        h2[0][hidx] = fmaxf(pre, 0.f);
    }
    __syncthreads();

    // ---- main sequential loop: iter t consumes h_t, emits out_t and h_{t+1}
    for (int t = 0; t < T_STEPS; ++t) {
        // every 32 steps: flush previous out window + prefetch next data window
        if ((t & 31) == 0) {
            if (t > 0 && tid < 96) {
                int w = (t>>5) - 1;
                float2 vv = ((const float2*)&obufF[w&1][0][0])[tid];
                size_t base = ((size_t)b*T_STEPS + (size_t)w*32)*6;
                if (f32) {
                    ((float2*)out)[base/2 + tid] = vv;
                } else {
                    unsigned int pa = __builtin_bit_cast(unsigned short, __float2bfloat16(vv.x));
                    unsigned int pbv = __builtin_bit_cast(unsigned short, __float2bfloat16(vv.y));
                    ((unsigned int*)((bf16*)out + base))[tid] = pa | (pbv << 16);
                }
            }
            if (tid < 96) {
                int k1 = (t>>5) + 1;
                int d = tid >> 4, c = tid & 15;
                int idx = k1*32 + c*2; if (idx > T_STEPS-2) idx = T_STEPS-2;
                float v0, v1;
                if (f32) {
                    float2 vv = *(const float2*)((const float*)data + dbase + (size_t)d*T_STEPS + idx);
                    v0 = vv.x; v1 = vv.y;
                } else {
                    unsigned int w = *(const unsigned int*)((const bf16*)data + dbase + (size_t)d*T_STEPS + idx);
                    v0 = __bfloat162float(__builtin_bit_cast(bf16, (unsigned short)(w & 0xFFFFu)));
                    v1 = __bfloat162float(__builtin_bit_cast(bf16, (unsigned short)(w >> 16)));
                }
                dbuf2[k1&1][c*2+0][d] = v0;
                dbuf2[k1&1][c*2+1][d] = v1;
            }
        }

        // phase 1: partial GEMV, M from registers, h chunk from LDS (conflict-free b128)
        const float* hrow = &h2[t&1][cg*36];
        float acc[8];
        #pragma unroll
        for (int r = 0; r < 8; ++r) acc[r] = 0.f;
        #pragma unroll
        for (int q = 0; q < 8; ++q) {
            float4 hv = ((const float4*)hrow)[q];
            #pragma unroll
            for (int r = 0; r < 8; ++r) {
                acc[r] = fmaf(Mreg[r][q*4+0], hv.x, acc[r]);
                acc[r] = fmaf(Mreg[r][q*4+1], hv.y, acc[r]);
                acc[r] = fmaf(Mreg[r][q*4+2], hv.z, acc[r]);
                acc[r] = fmaf(Mreg[r][q*4+3], hv.w, acc[r]);
            }
        }

        // reduce across the 8 lanes of the group (every lane ends with all 8 totals)
        #pragma unroll
        for (int r = 0; r < 8; ++r) {
            float v = acc[r];
            v = dpp_add<0xB1>(v);    // quad_perm [1,0,3,2]  (xor 1)
            v = dpp_add<0x4E>(v);    // quad_perm [2,3,0,1]  (xor 2)
            v = dpp_add<0x141>(v);   // row_half_mirror      (xor across quads of 8)
            acc[r] = v;
        }
        // lane cg selects total for its own row
        float s01 = (cg&1) ? acc[1] : acc[0];
        float s23 = (cg&1) ? acc[3] : acc[2];
        float s45 = (cg&1) ? acc[5] : acc[4];
        float s67 = (cg&1) ? acc[7] : acc[6];
        float s03 = (cg&2) ? s23 : s01;
        float s47 = (cg&2) ? s67 : s45;
        float sel = (cg&4) ? s47 : s03;

        // update: h_{t+1} = relu(z_{t+1} + cb + dproj_{t+1});  out_t = sel + b2d
        const float* dv = dbuf2[((t+1)>>5)&1][(t+1)&31];
        if (zrow) {
            float pre = sel + zc;
            #pragma unroll
            for (int d = 0; d < 6; ++d) pre = fmaf(w1dr[d], dv[d], pre);
            h2[(t+1)&1][hidx] = fmaxf(pre, 0.f);
        } else if (outlane) {
            obufF[(t>>5)&1][t&31][cg] = sel + b2dr;
        }
        __syncthreads();
    }

    // flush last out window (w = 255; covered by the final loop barrier)
    if (tid < 96) {
        float2 vv = ((const float2*)&obufF[1][0][0])[tid];
        size_t base = ((size_t)b*T_STEPS + (size_t)255*32)*6;
        if (f32) {
            ((float2*)out)[base/2 + tid] = vv;
        } else {
            unsigned int pa = __builtin_bit_cast(unsigned short, __float2bfloat16(vv.x));
            unsigned int pbv = __builtin_bit_cast(unsigned short, __float2bfloat16(vv.y));
            ((unsigned int*)((bf16*)out + base))[tid] = pa | (pbv << 16);
        }
    }
}

extern "C" void kernel_launch(void* const* d_in, const int* in_sizes, int n_in,
                              void* d_out, int out_size, void* d_ws, size_t ws_size,
                              hipStream_t stream) {
    const void* data = d_in[0];
    const void* W1d  = d_in[1];
    const void* b1d  = d_in[2];
    const void* W1p  = d_in[3];
    const void* b1p  = d_in[4];
    const void* W1c  = d_in[5];
    const void* b1c  = d_in[6];
    const void* W2d  = d_in[7];
    const void* b2d  = d_in[8];
    const void* W2c  = d_in[9];
    const void* b2c  = d_in[10];
    const void* pb   = d_in[11];

    size_t need = (size_t)SCRATCH_FLOATS * sizeof(float);
    float* Mbuf;
    if (ws_size >= need) {
        Mbuf = (float*)d_ws;
    } else {
        // fallback: park scratch in the tail of d_out (bf16 sizing = conservative
        // smaller region); it is consumed (reg-loaded) within ~us of rnn_run
        // start, before conflicting out-window flushes can reach it.
        size_t out_bytes = (size_t)B_NUM*T_STEPS*6*sizeof(bf16);
        Mbuf = (float*)((char*)d_out + ((out_bytes - need) & ~(size_t)255));
    }
    int* flagp = (int*)(Mbuf + FLAG_OFF);

    detect_dtype<<<1, 64, 0, stream>>>(data, flagp);
    build_M<<<(M_ELEMS + HID + 255)/256, 256, 0, stream>>>(W1c, W2c, b2c, W2d, Mbuf, flagp);
    rnn_run<<<B_NUM, 256, 0, stream>>>(data, W1d, b1d, W1p, b1p, b1c, b2d, pb,
                                       Mbuf, flagp, d_out);
}

// Round 3
// 6966.075 us; speedup vs baseline: 1.1957x; 1.1957x over previous
//
#include <hip/hip_runtime.h>
#include <hip/hip_bf16.h>
#include <stdint.h>

// RNNPB via per-step MFMA GEMM.
//   Recurrence folded: h_{t+1} = relu(M h_t + W1d d_{t+1} + (cb+m0) + W1p pb)
//                      out_t   = W2d h_t + b2d
// A (f16, 256x256) = rows: [0,240) h-rows, [240,246) out-rows (W2d), rest 0
//                    cols: [0,240) M / W2d, [240,246) W1d, 246 bias, 247-248 W1p
// Hx (f16, K=256 x N=16 batch) = [h_t ; d_{t+1} ; 1 ; pb ; 0-pad], per-block LDS.
// 2 blocks x 16 batch columns; 16 row-tiles x 8 K-frags = 128 mfma/step.
// A-fragments live in VGPR/AGPR (MFMA-native) -> no scratch spill (R2 lesson).

#define T_STEPS 8192
#define HID     240
#define CTX     180
#define RTOT    256
#define KTOT    256
#define KPAD    264                        // 264 halves: 33x16B rows -> odd stride, no LDS conflicts
#define A_HALVES (RTOT*KTOT)               // 65536
#define SCRATCH_BYTES (A_HALVES*2 + 16)    // A (f16) + flag

typedef __hip_bfloat16 bf16;
typedef _Float16 f16;
typedef _Float16 half8  __attribute__((ext_vector_type(8)));
typedef _Float16 half4v __attribute__((ext_vector_type(4)));
typedef float    f32x4  __attribute__((ext_vector_type(4)));
typedef float    f32x2  __attribute__((ext_vector_type(2)));
typedef unsigned int u32x2 __attribute__((ext_vector_type(2)));

__device__ __forceinline__ float ldin(const void* p, long i, bool f32) {
    return f32 ? ((const float*)p)[i] : __bfloat162float(((const bf16*)p)[i]);
}

// fp32 arrays: low half-words are random mantissa (huge-as-bf16 w.p. ~0.45/word)
// or all-zero (bf16-grid values). Real bf16 arrays: neither. (Verified R2: bf16.)
__global__ __launch_bounds__(64) void detect_dtype(const void* data, int* flag) {
    unsigned int w  = ((const unsigned int*)data)[threadIdx.x];
    unsigned int lo = w & 0xFFFFu;
    unsigned int ex = (lo >> 7) & 0xFFu;
    unsigned long long huge = __ballot(ex >= 0x8Eu);
    unsigned long long zero = __ballot(lo == 0u);
    if (threadIdx.x == 0) *flag = (huge != 0ull || zero == ~0ull) ? 1 : 0;
}

// ---------------- build augmented A (f16) ----------------
__global__ __launch_bounds__(256) void build_A(
    const void* __restrict__ W1d, const void* __restrict__ b1d,
    const void* __restrict__ W1p, const void* __restrict__ b1p,
    const void* __restrict__ W1c, const void* __restrict__ b1c,
    const void* __restrict__ W2d, const void* __restrict__ b2d,
    const void* __restrict__ W2c, const void* __restrict__ b2c,
    f16* __restrict__ Aa, const int* __restrict__ flagp)
{
    const bool f32 = (*flagp != 0);
    int idx = blockIdx.x*256 + threadIdx.x;      // 65536 total
    int r = idx >> 8, k = idx & 255;
    float v = 0.f;
    if (r < HID) {
        if (k < HID) {                           // M = W1c @ W2c
            float acc = 0.f;
            for (int c = 0; c < CTX; ++c)
                acc = fmaf(ldin(W1c, r*CTX+c, f32), ldin(W2c, c*HID+k, f32), acc);
            v = acc;
        } else if (k < 246) {                    // W1d columns (for d_{t+1})
            v = ldin(W1d, r*6 + (k-240), f32);
        } else if (k == 246) {                   // bias: b1d+b1c+b1p + W1c@b2c
            float m0 = 0.f;
            for (int c = 0; c < CTX; ++c)
                m0 = fmaf(ldin(W1c, r*CTX+c, f32), ldin(b2c, c, f32), m0);
            v = ldin(b1d, r, f32) + ldin(b1c, r, f32) + ldin(b1p, r, f32) + m0;
        } else if (k <= 248) {                   // W1p columns (pb rides in Hx)
            v = ldin(W1p, r*2 + (k-247), f32);
        }
    } else if (r < 246) {                        // out rows
        int o = r - 240;
        if (k < HID)       v = ldin(W2d, o*HID + k, f32);
        else if (k == 246) v = ldin(b2d, o, f32);
    }
    Aa[idx] = (f16)v;
}

// ---------------- per-step MFMA recurrent kernel: 2 blocks x 16 batches ----------------
__global__ __launch_bounds__(256, 1) void rnn_mfma(
    const void* __restrict__ data,   // [30][6][8192]
    const void* __restrict__ b1d, const void* __restrict__ W1p,
    const void* __restrict__ b1p, const void* __restrict__ b1c,
    const void* __restrict__ W1d, const void* __restrict__ pb,
    const f16* __restrict__ Aa, const int* __restrict__ flagp,
    void* __restrict__ out)          // [30][8192][6]
{
    const bool f32 = (*flagp != 0);
    const int tid  = threadIdx.x;
    const int w    = tid >> 6;       // wave 0..3: owns row-tiles 4w..4w+3
    const int l    = tid & 63;
    const int n16  = l & 15;         // batch column within block
    const int quad = l >> 4;
    const int base = blockIdx.x * 16;

    __shared__ __align__(16) f16   Hx[2][16][KPAD];      // 16,896 B
    __shared__ __align__(16) f16   dwin[2][16][6][32];   // 12,288 B (data windows, f16)
    __shared__ __align__(16) float obuf[2][32][16][6];   // 24,576 B (out staging, f32)

    // ---- zero Hx (rows 249..263 must stay 0; consts overwritten next phase)
    for (int i = tid; i < 2*16*KPAD; i += 256) ((f16*)Hx)[i] = (f16)0.f;
    __syncthreads();

    // ---- const rows (246:one, 247/248:pb) in both buffers; never rewritten
    if (tid < 32) {
        int bsel = tid >> 4, n = tid & 15;
        int bn = base + n; if (bn > 29) bn = 29;
        Hx[bsel][n][246] = (f16)1.0f;
        Hx[bsel][n][247] = (f16)ldin(pb, bn*2+0, f32);
        Hx[bsel][n][248] = (f16)ldin(pb, bn*2+1, f32);
    }
    // ---- h_0 = relu(cb + W1d d_0)   (no m0: z_0 = 0)
    for (int p = tid; p < HID*16; p += 256) {
        int n = p / HID, j = p - n*HID;
        int bn = base + n; if (bn > 29) bn = 29;
        float s = ldin(b1d, j, f32) + ldin(b1c, j, f32) + ldin(b1p, j, f32)
                + ldin(W1p, j*2+0, f32)*ldin(pb, bn*2+0, f32)
                + ldin(W1p, j*2+1, f32)*ldin(pb, bn*2+1, f32);
        for (int d = 0; d < 6; ++d)
            s = fmaf(ldin(W1d, j*6+d, f32), ldin(data, ((long)bn*6+d)*T_STEPS, f32), s);
        Hx[0][n][j] = (f16)fmaxf(s, 0.f);
    }
    // ---- stage data window 0: d-indices [1,32]
    if (tid < 96) {
        int n = tid & 15, dd = tid >> 4;
        int bn = base + n; if (bn > 29) bn = 29;
        long rowb = ((long)bn*6 + dd)*T_STEPS;
        for (int i = 0; i < 32; ++i)
            dwin[0][n][dd][i] = (f16)ldin(data, rowb + 1 + i, f32);
    }
    __syncthreads();
    if (tid < 96) {                              // Hx0 data rows = d_1
        int n = tid & 15, dd = tid >> 4;
        Hx[0][n][240+dd] = dwin[0][n][dd][0];
    }

    // ---- persistent A fragments: A[m][k], m = tile*16 + (lane&15), k = q*32+quad*8+e
    half8 af[4][8];
    #pragma unroll
    for (int i = 0; i < 4; ++i) {
        int m = (w*4 + i)*16 + n16;
        #pragma unroll
        for (int q = 0; q < 8; ++q)
            af[i][q] = *(const half8*)(Aa + (size_t)m*KTOT + q*32 + quad*8);
    }
    __syncthreads();

    // ---- main loop: step t consumes Hx[cur] (h_t, d_{t+1}) -> out_t, h_{t+1}
    for (int t = 0; t < T_STEPS; ++t) {
        const int cur = t & 1, nxt = cur ^ 1;

        if ((t & 31) == 0) {
            const int u = t >> 5;
            if (u > 0) {                         // flush out window u-1
                const int ob = (u-1) & 1;
                int n = tid >> 4, i = tid & 15;
                int bn = base + n;
                if (bn <= 29) {
                    float v[12];
                    #pragma unroll
                    for (int jj = 0; jj < 6; ++jj) {
                        v[jj]   = obuf[ob][2*i  ][n][jj];
                        v[6+jj] = obuf[ob][2*i+1][n][jj];
                    }
                    long gb = (long)bn*T_STEPS*6 + (long)(u-1)*192 + i*12;
                    if (f32) {
                        float* op = (float*)out + gb;
                        f32x4 a = {v[0],v[1],v[2],v[3]};
                        f32x4 b = {v[4],v[5],v[6],v[7]};
                        f32x4 c = {v[8],v[9],v[10],v[11]};
                        *(f32x4*)(op+0) = a; *(f32x4*)(op+4) = b; *(f32x4*)(op+8) = c;
                    } else {
                        bf16* op = (bf16*)out + gb;
                        unsigned int pk[6];
                        #pragma unroll
                        for (int jj = 0; jj < 6; ++jj) {
                            unsigned int a = (unsigned int)__builtin_bit_cast(unsigned short, __float2bfloat16(v[2*jj]));
                            unsigned int b = (unsigned int)__builtin_bit_cast(unsigned short, __float2bfloat16(v[2*jj+1]));
                            pk[jj] = a | (b << 16);
                        }
                        u32x2 x = {pk[0], pk[1]}, y = {pk[2], pk[3]}, z = {pk[4], pk[5]};
                        *(u32x2*)(op+0) = x; *(u32x2*)(op+4) = y; *(u32x2*)(op+8) = z;
                    }
                }
            }
            if (tid < 96) {                      // prefetch window u+1: d-range [32u+33, 32u+64]
                int n = tid & 15, dd = tid >> 4;
                int bn = base + n; if (bn > 29) bn = 29;
                long rowb = ((long)bn*6 + dd)*T_STEPS;
                int gs = 32*(u+1) + 1;
                f16* dst = dwin[(u+1)&1][n][dd];
                for (int i = 0; i < 32; ++i) {
                    int g = gs + i; if (g > T_STEPS-1) g = T_STEPS-1;
                    dst[i] = (f16)ldin(data, rowb + g, f32);
                }
            }
        }

        // B fragments: B[k][n], n = lane&15, k = q*32 + quad*8 + e
        half8 bfr[8];
        #pragma unroll
        for (int q = 0; q < 8; ++q)
            bfr[q] = *(const half8*)&Hx[cur][n16][q*32 + quad*8];

        f32x4 acc[4];
        #pragma unroll
        for (int i = 0; i < 4; ++i) { f32x4 z = {0.f,0.f,0.f,0.f}; acc[i] = z; }
        #pragma unroll
        for (int q = 0; q < 8; ++q) {
            #pragma unroll
            for (int i = 0; i < 4; ++i)
                acc[i] = __builtin_amdgcn_mfma_f32_16x16x32_f16(af[i][q], bfr[q], acc[i], 0, 0, 0);
        }

        // data rows of next Hx = d_{t+2}
        if (tid < 96) {
            int n = tid & 15, dd = tid >> 4;
            Hx[nxt][n][240+dd] = dwin[((t+1)>>5)&1][n][dd][(t+1)&31];
        }

        // epilogue: D col = lane&15 (batch), row = tile*16 + quad*4 + reg
        #pragma unroll
        for (int i = 0; i < 4; ++i) {
            int rt = w*4 + i;
            if (rt < 15) {                       // h rows -> relu -> f16 -> Hx[nxt]
                half4v hv;
                hv.x = (f16)fmaxf(acc[i].x, 0.f);
                hv.y = (f16)fmaxf(acc[i].y, 0.f);
                hv.z = (f16)fmaxf(acc[i].z, 0.f);
                hv.w = (f16)fmaxf(acc[i].w, 0.f);
                *(half4v*)&Hx[nxt][n16][rt*16 + quad*4] = hv;
            } else {                             // tile 15: rows 240..245 = out_t
                if (quad == 0) {
                    f32x2 a = {acc[i].x, acc[i].y}, b = {acc[i].z, acc[i].w};
                    *(f32x2*)&obuf[(t>>5)&1][t&31][n16][0] = a;
                    *(f32x2*)&obuf[(t>>5)&1][t&31][n16][2] = b;
                } else if (quad == 1) {
                    f32x2 a = {acc[i].x, acc[i].y};
                    *(f32x2*)&obuf[(t>>5)&1][t&31][n16][4] = a;
                }
            }
        }
        __syncthreads();
    }

    // ---- final flush: window 255 (slot 1)
    {
        int n = tid >> 4, i = tid & 15;
        int bn = base + n;
        if (bn <= 29) {
            float v[12];
            #pragma unroll
            for (int jj = 0; jj < 6; ++jj) {
                v[jj]   = obuf[1][2*i  ][n][jj];
                v[6+jj] = obuf[1][2*i+1][n][jj];
            }
            long gb = (long)bn*T_STEPS*6 + (long)255*192 + i*12;
            if (f32) {
                float* op = (float*)out + gb;
                f32x4 a = {v[0],v[1],v[2],v[3]};
                f32x4 b = {v[4],v[5],v[6],v[7]};
                f32x4 c = {v[8],v[9],v[10],v[11]};
                *(f32x4*)(op+0) = a; *(f32x4*)(op+4) = b; *(f32x4*)(op+8) = c;
            } else {
                bf16* op = (bf16*)out + gb;
                unsigned int pk[6];
                #pragma unroll
                for (int jj = 0; jj < 6; ++jj) {
                    unsigned int a = (unsigned int)__builtin_bit_cast(unsigned short, __float2bfloat16(v[2*jj]));
                    unsigned int b = (unsigned int)__builtin_bit_cast(unsigned short, __float2bfloat16(v[2*jj+1]));
                    pk[jj] = a | (b << 16);
                }
                u32x2 x = {pk[0], pk[1]}, y = {pk[2], pk[3]}, z = {pk[4], pk[5]};
                *(u32x2*)(op+0) = x; *(u32x2*)(op+4) = y; *(u32x2*)(op+8) = z;
            }
        }
    }
}

extern "C" void kernel_launch(void* const* d_in, const int* in_sizes, int n_in,
                              void* d_out, int out_size, void* d_ws, size_t ws_size,
                              hipStream_t stream) {
    const void* data = d_in[0];
    const void* W1d  = d_in[1];
    const void* b1d  = d_in[2];
    const void* W1p  = d_in[3];
    const void* b1p  = d_in[4];
    const void* W1c  = d_in[5];
    const void* b1c  = d_in[6];
    const void* W2d  = d_in[7];
    const void* b2d  = d_in[8];
    const void* W2c  = d_in[9];
    const void* b2c  = d_in[10];
    const void* pb   = d_in[11];

    size_t need = SCRATCH_BYTES;
    char* scratch;
    if (ws_size >= need) {
        scratch = (char*)d_ws;
    } else {
        // park in out-tail (bf16 sizing = conservative); A is consumed into
        // registers pre-loop, ~1ms before any flush can reach this region.
        size_t out_bytes = (size_t)30*T_STEPS*6*sizeof(bf16);
        scratch = (char*)d_out + ((out_bytes - need) & ~(size_t)255);
    }
    f16* Aa   = (f16*)scratch;
    int* flagp = (int*)(scratch + A_HALVES*2);

    detect_dtype<<<1, 64, 0, stream>>>(data, flagp);
    build_A<<<A_HALVES/256, 256, 0, stream>>>(W1d, b1d, W1p, b1p, W1c, b1c,
                                              W2d, b2d, W2c, b2c, Aa, flagp);
    rnn_mfma<<<2, 256, 0, stream>>>(data, b1d, W1p, b1p, b1c, W1d, pb,
                                    Aa, flagp, d_out);
}

// Round 4
// 5599.242 us; speedup vs baseline: 1.4876x; 1.2441x over previous
//
#include <hip/hip_runtime.h>
#include <hip/hip_bf16.h>
#include <stdint.h>

// RNNPB via per-step MFMA GEMM (R4: LDS-lean).
//   h_{t+1} = relu(M h_t + W1d d_{t+1} + cb' + W1p pb),  out_t = W2d h_t + b2d
// A (f16, 256x256): rows [0,240) h, [240,246) out (W2d); cols [0,240) M/W2d,
//   [240,246) W1d, 246 bias, 247/248 W1p, 249+ zero.
// B per step: k 0..239 = h (LDS Hx, stride 248 -> uniform superbanks),
//   k 240..247 = {d_{t+1},1,pb0} (LDS dwin, one b128), k 248.. = {pb1,0..} (reg).
// Data prefetched to REGISTERS one 32-step window ahead; out stored directly.

#define T_STEPS 8192
#define HID     240
#define CTX     180
#define KTOT    256
#define HXROW   248                        // halves/row: (248/8)=31 odd -> conflict-free b128
#define HXBUF   (16*HXROW)                 // 3968 halves per buffer
#define A_HALVES (256*256)
#define SCRATCH_BYTES (A_HALVES*2 + 16)

typedef __hip_bfloat16 bf16;
typedef _Float16 f16;
typedef _Float16 half8  __attribute__((ext_vector_type(8)));
typedef _Float16 half4v __attribute__((ext_vector_type(4)));
typedef float    f32x4  __attribute__((ext_vector_type(4)));
typedef float    f32x2  __attribute__((ext_vector_type(2)));
typedef unsigned int uint4v __attribute__((ext_vector_type(4)));

__device__ __forceinline__ float ldin(const void* p, long i, bool f32) {
    return f32 ? ((const float*)p)[i] : __bfloat162float(((const bf16*)p)[i]);
}
__device__ __forceinline__ unsigned pkbf(float a, float b) {
    unsigned ua = (unsigned)__builtin_bit_cast(unsigned short, __float2bfloat16(a));
    unsigned ub = (unsigned)__builtin_bit_cast(unsigned short, __float2bfloat16(b));
    return ua | (ub << 16);
}

// fp32 arrays: low half-words are random mantissa (huge-as-bf16 w.p. ~0.45/word)
// or all-zero (bf16-grid). Real bf16 arrays: neither. (Verified R2/R3: bf16 path.)
__global__ __launch_bounds__(64) void detect_dtype(const void* data, int* flag) {
    unsigned int w  = ((const unsigned int*)data)[threadIdx.x];
    unsigned int lo = w & 0xFFFFu;
    unsigned int ex = (lo >> 7) & 0xFFu;
    unsigned long long huge = __ballot(ex >= 0x8Eu);
    unsigned long long zero = __ballot(lo == 0u);
    if (threadIdx.x == 0) *flag = (huge != 0ull || zero == ~0ull) ? 1 : 0;
}

// ---------------- build augmented A (f16) ----------------
__global__ __launch_bounds__(256) void build_A(
    const void* __restrict__ W1d, const void* __restrict__ b1d,
    const void* __restrict__ W1p, const void* __restrict__ b1p,
    const void* __restrict__ W1c, const void* __restrict__ b1c,
    const void* __restrict__ W2d, const void* __restrict__ b2d,
    const void* __restrict__ W2c, const void* __restrict__ b2c,
    f16* __restrict__ Aa, const int* __restrict__ flagp)
{
    const bool f32 = (*flagp != 0);
    int idx = blockIdx.x*256 + threadIdx.x;      // 65536 total
    int r = idx >> 8, k = idx & 255;
    float v = 0.f;
    if (r < HID) {
        if (k < HID) {                           // M = W1c @ W2c
            float acc = 0.f;
            for (int c = 0; c < CTX; ++c)
                acc = fmaf(ldin(W1c, r*CTX+c, f32), ldin(W2c, c*HID+k, f32), acc);
            v = acc;
        } else if (k < 246) {                    // W1d columns (for d_{t+1})
            v = ldin(W1d, r*6 + (k-240), f32);
        } else if (k == 246) {                   // bias: b1d+b1c+b1p + W1c@b2c
            float m0 = 0.f;
            for (int c = 0; c < CTX; ++c)
                m0 = fmaf(ldin(W1c, r*CTX+c, f32), ldin(b2c, c, f32), m0);
            v = ldin(b1d, r, f32) + ldin(b1c, r, f32) + ldin(b1p, r, f32) + m0;
        } else if (k <= 248) {                   // W1p columns
            v = ldin(W1p, r*2 + (k-247), f32);
        }
    } else if (r < 246) {                        // out rows
        int o = r - 240;
        if (k < HID)       v = ldin(W2d, o*HID + k, f32);
        else if (k == 246) v = ldin(b2d, o, f32);
    }
    Aa[idx] = (f16)v;
}

// ---------------- per-step MFMA recurrent kernel: 2 blocks x 16 batches ----------------
__global__ __launch_bounds__(256, 1) void rnn_mfma(
    const void* __restrict__ data,   // [30][6][8192]
    const void* __restrict__ b1d, const void* __restrict__ W1p,
    const void* __restrict__ b1p, const void* __restrict__ b1c,
    const void* __restrict__ W1d, const void* __restrict__ pb,
    const f16* __restrict__ Aa, const int* __restrict__ flagp,
    void* __restrict__ out)          // [30][8192][6]
{
    const bool f32 = (*flagp != 0);
    const int tid  = threadIdx.x;
    const int w    = tid >> 6;       // wave: row-tiles 4w..4w+3 (tile 15 = out rows)
    const int l    = tid & 63;
    const int n16  = l & 15;         // batch column
    const int quad = l >> 4;
    const int base = blockIdx.x * 16;
    const int bn   = base + n16;
    const bool bvalid = (bn < 30);
    const int bnc  = bvalid ? bn : 29;

    __shared__ __align__(16) f16 Hx[2*HXBUF];        // 15,872 B (h only; pads never read)
    __shared__ __align__(16) f16 dwin[2][32][16][8]; // 16,384 B ({d0..d5,1,pb0} per t,n)
    __shared__ __align__(16) f16 zrow[8];            // zeros for quad3's b128

    if (tid < 8) zrow[tid] = (f16)0.f;

    // const slots 6 (=1.0) and 7 (=pb0) of every dwin entry; fills only touch 0..5
    for (int i = tid; i < 2*32*16; i += 256) {
        int buf = i >> 9, rem = i & 511, sl = rem >> 4, n = rem & 15;
        int nb = base + n; if (nb > 29) nb = 29;
        dwin[buf][sl][n][6] = (f16)1.0f;
        dwin[buf][sl][n][7] = (f16)ldin(pb, nb*2+0, f32);
    }

    // ---- h_0 = relu(cb + W1d d_0)   (z_0 = 0)
    for (int p = tid; p < HID*16; p += 256) {
        int n = p / HID, j = p - n*HID;
        int nb = base + n; if (nb > 29) nb = 29;
        float s = ldin(b1d, j, f32) + ldin(b1c, j, f32) + ldin(b1p, j, f32)
                + ldin(W1p, j*2+0, f32)*ldin(pb, nb*2+0, f32)
                + ldin(W1p, j*2+1, f32)*ldin(pb, nb*2+1, f32);
        for (int d = 0; d < 6; ++d)
            s = fmaf(ldin(W1d, j*6+d, f32), ldin(data, ((long)nb*6+d)*T_STEPS, f32), s);
        Hx[n*HXROW + j] = (f16)fmaxf(s, 0.f);
    }

    // ---- window 0 (g = 1..32), scalar one-time fill
    const int pn = tid & 15, pd = tid >> 4;          // prefetch lane role (tid<96)
    int pnb = base + pn; if (pnb > 29) pnb = 29;
    const long prow = ((long)pnb*6 + pd)*T_STEPS;    // element row base for (pnb,pd)
    if (tid < 96) {
        for (int i = 0; i < 32; ++i)
            dwin[0][i][pn][pd] = (f16)ldin(data, prow + 1 + i, f32);
    }

    // ---- issue register span for window 1: halves g in [32,64) + dword {64,65}
    uint4v sp4[4]; unsigned spx = 0;
    if (tid < 96 && !f32) {
        const unsigned short* dp = (const unsigned short*)data + prow + 32;
        sp4[0] = ((const uint4v*)dp)[0];
        sp4[1] = ((const uint4v*)dp)[1];
        sp4[2] = ((const uint4v*)dp)[2];
        sp4[3] = ((const uint4v*)dp)[3];
        spx = *(const unsigned*)(dp + 32);
    }

    // ---- persistent A fragments: A[m][k], m = tile*16+n16, k = q*32+quad*8+e
    half8 af[4][8];
    #pragma unroll
    for (int i = 0; i < 4; ++i) {
        int m = (w*4 + i)*16 + n16;
        #pragma unroll
        for (int q = 0; q < 8; ++q)
            af[i][q] = *(const half8*)(Aa + (size_t)m*KTOT + q*32 + quad*8);
    }
    // drain A reads before any wave can store into the (possible) d_out-tail scratch
    asm volatile("s_waitcnt vmcnt(0)" ::: "memory");
    __syncthreads();

    const f16* hxread0 = Hx + n16*HXROW + quad*8;    // + cur*HXBUF + q*32
    f16*       hxw     = Hx + n16*HXROW + quad*4;    // + nxt*HXBUF + rt*16
    const f16  pb1h    = (f16)ldin(pb, bnc*2+1, f32);

    for (int t = 0; t < T_STEPS; ++t) {
        const int cur = t & 1, nxt = cur ^ 1;

        // ---- window boundary: consume reg-span -> dwin[(u+1)&1]; issue next span
        if ((t & 31) == 0) {
            const int u = t >> 5;
            if (tid < 96) {
                f16* dst = &dwin[(u+1)&1][0][pn][pd];          // slot stride 128 halves
                if (!f32) {
                    unsigned dws[17] = {sp4[0].x, sp4[0].y, sp4[0].z, sp4[0].w,
                                        sp4[1].x, sp4[1].y, sp4[1].z, sp4[1].w,
                                        sp4[2].x, sp4[2].y, sp4[2].z, sp4[2].w,
                                        sp4[3].x, sp4[3].y, sp4[3].z, sp4[3].w, spx};
                    #pragma unroll
                    for (int i = 0; i < 32; ++i) {
                        int jj = i + 1;                        // slot i <- g = 32u+33+i
                        unsigned hv = (dws[jj >> 1] >> ((jj & 1)*16)) & 0xFFFFu;
                        float fv = __builtin_bit_cast(float, hv << 16);
                        dst[i*128] = (f16)fv;
                    }
                    int gs = 32*u + 64; if (gs > 8160) gs = 8160;   // 16B-aligned, in-bounds
                    const unsigned short* dp = (const unsigned short*)data + prow + gs;
                    sp4[0] = ((const uint4v*)dp)[0];
                    sp4[1] = ((const uint4v*)dp)[1];
                    sp4[2] = ((const uint4v*)dp)[2];
                    sp4[3] = ((const uint4v*)dp)[3];
                    int gx = gs + 32; if (gx > 8190) gx = 8190;
                    spx = *(const unsigned*)((const unsigned short*)data + prow + gx);
                } else {
                    // fp32 fallback (unused in practice): synchronous fill
                    for (int i = 0; i < 32; ++i) {
                        long g = 32*(long)u + 33 + i; if (g > 8191) g = 8191;
                        dst[i*128] = (f16)((const float*)data)[prow + g];
                    }
                }
            }
        }

        // ---- B fragments
        const f16* hxc = hxread0 + cur*HXBUF;
        half8 bfr[8];
        #pragma unroll
        for (int q = 0; q < 7; ++q) bfr[q] = *(const half8*)(hxc + q*32);
        {
            const f16* b7;
            if (quad < 2)       b7 = hxc + 7*32;               // h rows 224..239
            else if (quad == 2) b7 = &dwin[(t>>5)&1][t&31][n16][0];
            else                b7 = zrow;
            half8 bb = *(const half8*)b7;
            if (quad == 3) bb[0] = pb1h;                       // k=248 = pb1; 249+ x 0-cols
            bfr[7] = bb;
        }

        // ---- GEMM: 4 independent 8-deep chains
        f32x4 acc[4];
        #pragma unroll
        for (int i = 0; i < 4; ++i) { f32x4 z = {0.f,0.f,0.f,0.f}; acc[i] = z; }
        #pragma unroll
        for (int q = 0; q < 8; ++q) {
            #pragma unroll
            for (int i = 0; i < 4; ++i)
                acc[i] = __builtin_amdgcn_mfma_f32_16x16x32_f16(af[i][q], bfr[q], acc[i], 0, 0, 0);
        }

        // ---- epilogue: h rows -> relu -> Hx[nxt]; out rows -> global (fire&forget)
        f16* hxn = hxw + nxt*HXBUF;
        #pragma unroll
        for (int i = 0; i < 4; ++i) {
            int rt = w*4 + i;
            if (rt < 15) {
                half4v hv;
                hv.x = (f16)fmaxf(acc[i].x, 0.f);
                hv.y = (f16)fmaxf(acc[i].y, 0.f);
                hv.z = (f16)fmaxf(acc[i].z, 0.f);
                hv.w = (f16)fmaxf(acc[i].w, 0.f);
                *(half4v*)(hxn + rt*16) = hv;                  // 2-way banks = free
            } else if (bvalid) {                               // rt==15: rows 240..247
                long ob = ((long)bn*T_STEPS + t)*6;
                if (quad == 0) {                               // out elems 0..3
                    if (!f32) {
                        bf16* op = (bf16*)out + ob;
                        *(unsigned*)(op)     = pkbf(acc[i].x, acc[i].y);
                        *(unsigned*)(op + 2) = pkbf(acc[i].z, acc[i].w);
                    } else {
                        float* op = (float*)out + ob;
                        f32x2 p0 = {acc[i].x, acc[i].y}; *(f32x2*)(op)     = p0;
                        f32x2 p1 = {acc[i].z, acc[i].w}; *(f32x2*)(op + 2) = p1;
                    }
                } else if (quad == 1) {                        // out elems 4,5
                    if (!f32) {
                        bf16* op = (bf16*)out + ob;
                        *(unsigned*)(op + 4) = pkbf(acc[i].x, acc[i].y);
                    } else {
                        float* op = (float*)out + ob;
                        f32x2 p0 = {acc[i].x, acc[i].y}; *(f32x2*)(op + 4) = p0;
                    }
                }
            }
        }
        __syncthreads();
    }
}

extern "C" void kernel_launch(void* const* d_in, const int* in_sizes, int n_in,
                              void* d_out, int out_size, void* d_ws, size_t ws_size,
                              hipStream_t stream) {
    const void* data = d_in[0];
    const void* W1d  = d_in[1];
    const void* b1d  = d_in[2];
    const void* W1p  = d_in[3];
    const void* b1p  = d_in[4];
    const void* W1c  = d_in[5];
    const void* b1c  = d_in[6];
    const void* W2d  = d_in[7];
    const void* b2d  = d_in[8];
    const void* W2c  = d_in[9];
    const void* b2c  = d_in[10];
    const void* pb   = d_in[11];

    size_t need = SCRATCH_BYTES;
    char* scratch;
    if (ws_size >= need) {
        scratch = (char*)d_ws;
    } else {
        // park A in out-tail (bf16 sizing); rnn_mfma drains its A reads
        // (s_waitcnt vmcnt(0) before the first barrier) before any out-store.
        size_t out_bytes = (size_t)30*T_STEPS*6*sizeof(bf16);
        scratch = (char*)d_out + ((out_bytes - need) & ~(size_t)255);
    }
    f16* Aa    = (f16*)scratch;
    int* flagp = (int*)(scratch + A_HALVES*2);

    detect_dtype<<<1, 64, 0, stream>>>(data, flagp);
    build_A<<<A_HALVES/256, 256, 0, stream>>>(W1d, b1d, W1p, b1p, W1c, b1c,
                                              W2d, b2d, W2c, b2c, Aa, flagp);
    rnn_mfma<<<2, 256, 0, stream>>>(data, b1d, W1p, b1p, b1c, W1d, pb,
                                    Aa, flagp, d_out);
}

// Round 5
// 5043.178 us; speedup vs baseline: 1.6516x; 1.1103x over previous
//
#include <hip/hip_runtime.h>
#include <hip/hip_bf16.h>
#include <stdint.h>

// RNNPB via per-step MFMA GEMM (R5: 8 waves + lgkm-only barrier).
//   h_{t+1} = relu(M h_t + W1d d_{t+1} + cb' + W1p pb),  out_t = W2d h_t + b2d
// A (f16, 256x256): rows [0,240) h, [240,246) out (W2d); cols [0,240) M/W2d,
//   [240,246) W1d, 246 bias, 247/248 W1p, 249+ zero.
// B per step: k 0..239 = h (LDS Hx, stride 248), k 240..247 = {d_{t+1},1,pb0}
//   (LDS dwin b128), k 248.. = {pb1,0..} (reg). Data prefetched to REGISTERS a
//   32-step window ahead; outs stored direct to global, never drained at the
//   barrier (raw s_barrier + lgkmcnt(0) only -- __syncthreads would vmcnt(0)).
// 2 blocks x 16 batches; 8 waves/block (2/SIMD) x 2 row-tiles x 8 K-frags.

#define T_STEPS 8192
#define HID     240
#define CTX     180
#define KTOT    256
#define HXROW   248                        // halves/row: 31 dwords-odd -> clean b128 spread
#define HXBUF   (16*HXROW)
#define A_HALVES (256*256)
#define SCRATCH_BYTES (A_HALVES*2 + 16)

typedef __hip_bfloat16 bf16;
typedef _Float16 f16;
typedef _Float16 half8  __attribute__((ext_vector_type(8)));
typedef _Float16 half4v __attribute__((ext_vector_type(4)));
typedef float    f32x4  __attribute__((ext_vector_type(4)));
typedef float    f32x2  __attribute__((ext_vector_type(2)));
typedef unsigned int uint4v __attribute__((ext_vector_type(4)));

__device__ __forceinline__ float ldin(const void* p, long i, bool f32) {
    return f32 ? ((const float*)p)[i] : __bfloat162float(((const bf16*)p)[i]);
}
__device__ __forceinline__ unsigned pkbf(float a, float b) {
    unsigned ua = (unsigned)__builtin_bit_cast(unsigned short, __float2bfloat16(a));
    unsigned ub = (unsigned)__builtin_bit_cast(unsigned short, __float2bfloat16(b));
    return ua | (ub << 16);
}
// LDS-ordering barrier WITHOUT vmem drain (out-stores/prefetch stay in flight)
__device__ __forceinline__ void barrier_lds() {
    asm volatile("s_waitcnt lgkmcnt(0)\n\ts_barrier" ::: "memory");
}

// fp32 arrays: low half-words are random mantissa (huge-as-bf16 w.p. ~0.45/word)
// or all-zero (bf16-grid). Real bf16 arrays: neither. (Verified R2-R4: bf16 path.)
__global__ __launch_bounds__(64) void detect_dtype(const void* data, int* flag) {
    unsigned int w  = ((const unsigned int*)data)[threadIdx.x];
    unsigned int lo = w & 0xFFFFu;
    unsigned int ex = (lo >> 7) & 0xFFu;
    unsigned long long huge = __ballot(ex >= 0x8Eu);
    unsigned long long zero = __ballot(lo == 0u);
    if (threadIdx.x == 0) *flag = (huge != 0ull || zero == ~0ull) ? 1 : 0;
}

// ---------------- build augmented A (f16) ----------------
__global__ __launch_bounds__(256) void build_A(
    const void* __restrict__ W1d, const void* __restrict__ b1d,
    const void* __restrict__ W1p, const void* __restrict__ b1p,
    const void* __restrict__ W1c, const void* __restrict__ b1c,
    const void* __restrict__ W2d, const void* __restrict__ b2d,
    const void* __restrict__ W2c, const void* __restrict__ b2c,
    f16* __restrict__ Aa, const int* __restrict__ flagp)
{
    const bool f32 = (*flagp != 0);
    int idx = blockIdx.x*256 + threadIdx.x;
    int r = idx >> 8, k = idx & 255;
    float v = 0.f;
    if (r < HID) {
        if (k < HID) {                           // M = W1c @ W2c
            float acc = 0.f;
            for (int c = 0; c < CTX; ++c)
                acc = fmaf(ldin(W1c, r*CTX+c, f32), ldin(W2c, c*HID+k, f32), acc);
            v = acc;
        } else if (k < 246) {                    // W1d columns
            v = ldin(W1d, r*6 + (k-240), f32);
        } else if (k == 246) {                   // bias: b1d+b1c+b1p + W1c@b2c
            float m0 = 0.f;
            for (int c = 0; c < CTX; ++c)
                m0 = fmaf(ldin(W1c, r*CTX+c, f32), ldin(b2c, c, f32), m0);
            v = ldin(b1d, r, f32) + ldin(b1c, r, f32) + ldin(b1p, r, f32) + m0;
        } else if (k <= 248) {                   // W1p columns
            v = ldin(W1p, r*2 + (k-247), f32);
        }
    } else if (r < 246) {                        // out rows
        int o = r - 240;
        if (k < HID)       v = ldin(W2d, o*HID + k, f32);
        else if (k == 246) v = ldin(b2d, o, f32);
    }
    Aa[idx] = (f16)v;
}

// ---------------- per-step MFMA recurrent kernel: 2 blocks x 16 batches ----------------
__global__ __launch_bounds__(512, 2) void rnn_mfma(
    const void* __restrict__ data,   // [30][6][8192]
    const void* __restrict__ b1d, const void* __restrict__ W1p,
    const void* __restrict__ b1p, const void* __restrict__ b1c,
    const void* __restrict__ W1d, const void* __restrict__ pb,
    const f16* __restrict__ Aa, const int* __restrict__ flagp,
    void* __restrict__ out)          // [30][8192][6]
{
    const bool f32 = (*flagp != 0);
    const int tid  = threadIdx.x;
    const int w    = tid >> 6;       // wave 0..7: row-tiles {2w, 2w+1}; wave7 tile15 = out
    const int l    = tid & 63;
    const int n16  = l & 15;
    const int quad = l >> 4;
    const int base = blockIdx.x * 16;
    const int bn   = base + n16;
    const bool bvalid = (bn < 30);
    const int bnc  = bvalid ? bn : 29;

    __shared__ __align__(16) f16 Hx[2*HXBUF];        // 15,872 B
    __shared__ __align__(16) f16 dwin[2][32][16][8]; // 16,384 B
    __shared__ __align__(16) f16 zrow[8];

    if (tid < 8) zrow[tid] = (f16)0.f;

    // const slots 6 (=1.0) and 7 (=pb0); fills only touch 0..5
    for (int i = tid; i < 2*32*16; i += 512) {
        int buf = i >> 9, rem = i & 511, sl = rem >> 4, n = rem & 15;
        int nb = base + n; if (nb > 29) nb = 29;
        dwin[buf][sl][n][6] = (f16)1.0f;
        dwin[buf][sl][n][7] = (f16)ldin(pb, nb*2+0, f32);
    }

    // ---- h_0 = relu(cb + W1d d_0)
    for (int p = tid; p < HID*16; p += 512) {
        int n = p / HID, j = p - n*HID;
        int nb = base + n; if (nb > 29) nb = 29;
        float s = ldin(b1d, j, f32) + ldin(b1c, j, f32) + ldin(b1p, j, f32)
                + ldin(W1p, j*2+0, f32)*ldin(pb, nb*2+0, f32)
                + ldin(W1p, j*2+1, f32)*ldin(pb, nb*2+1, f32);
        for (int d = 0; d < 6; ++d)
            s = fmaf(ldin(W1d, j*6+d, f32), ldin(data, ((long)nb*6+d)*T_STEPS, f32), s);
        Hx[n*HXROW + j] = (f16)fmaxf(s, 0.f);
    }

    // ---- window 0 (g = 1..32): one-time scalar fill (prefetch lanes = tid<96)
    const int pn = tid & 15, pd = tid >> 4;
    int pnb = base + pn; if (pnb > 29) pnb = 29;
    const long prow = ((long)pnb*6 + (pd < 6 ? pd : 0))*T_STEPS;
    if (tid < 96) {
        for (int i = 0; i < 32; ++i)
            dwin[0][i][pn][pd] = (f16)ldin(data, prow + 1 + i, f32);
    }

    // ---- register span for window 1: halves g in [32,64) + dword {64,65}
    uint4v sp4[4]; unsigned spx = 0;
    if (tid < 96 && !f32) {
        const unsigned short* dp = (const unsigned short*)data + prow + 32;
        sp4[0] = ((const uint4v*)dp)[0];
        sp4[1] = ((const uint4v*)dp)[1];
        sp4[2] = ((const uint4v*)dp)[2];
        sp4[3] = ((const uint4v*)dp)[3];
        spx = *(const unsigned*)(dp + 32);
    }

    // ---- persistent A fragments: tiles 2w, 2w+1
    half8 af[2][8];
    #pragma unroll
    for (int i = 0; i < 2; ++i) {
        int m = (w*2 + i)*16 + n16;
        #pragma unroll
        for (int q = 0; q < 8; ++q)
            af[i][q] = *(const half8*)(Aa + (size_t)m*KTOT + q*32 + quad*8);
    }
    // drain A reads before any wave can store into the (possible) d_out-tail scratch
    asm volatile("s_waitcnt vmcnt(0)" ::: "memory");
    __syncthreads();

    const f16* hxread0 = Hx + n16*HXROW + quad*8;
    f16*       hxw     = Hx + n16*HXROW + quad*4;
    const f16  pb1h    = (f16)ldin(pb, bnc*2+1, f32);

    for (int t2 = 0; t2 < T_STEPS; t2 += 2) {
        #pragma unroll
        for (int s = 0; s < 2; ++s) {
            const int t = t2 + s;
            const int cur = s, nxt = s ^ 1;      // compile-time buffer parity

            // ---- window boundary (t even only): consume reg-span, issue next
            if (s == 0 && (t & 31) == 0) {
                const int u = t >> 5;
                if (tid < 96) {
                    f16* dst = &dwin[(u+1)&1][0][pn][pd];      // slot stride 128 halves
                    if (!f32) {
                        unsigned dws[17] = {sp4[0].x, sp4[0].y, sp4[0].z, sp4[0].w,
                                            sp4[1].x, sp4[1].y, sp4[1].z, sp4[1].w,
                                            sp4[2].x, sp4[2].y, sp4[2].z, sp4[2].w,
                                            sp4[3].x, sp4[3].y, sp4[3].z, sp4[3].w, spx};
                        #pragma unroll
                        for (int i = 0; i < 32; ++i) {
                            int jj = i + 1;                    // slot i <- g = 32u+33+i
                            unsigned hv = (dws[jj >> 1] >> ((jj & 1)*16)) & 0xFFFFu;
                            float fv = __builtin_bit_cast(float, hv << 16);
                            dst[i*128] = (f16)fv;
                        }
                        int gs = 32*u + 64; if (gs > 8160) gs = 8160;
                        const unsigned short* dp = (const unsigned short*)data + prow + gs;
                        sp4[0] = ((const uint4v*)dp)[0];
                        sp4[1] = ((const uint4v*)dp)[1];
                        sp4[2] = ((const uint4v*)dp)[2];
                        sp4[3] = ((const uint4v*)dp)[3];
                        int gx = gs + 32; if (gx > 8190) gx = 8190;
                        spx = *(const unsigned*)((const unsigned short*)data + prow + gx);
                    } else {
                        for (int i = 0; i < 32; ++i) {
                            long g = 32*(long)u + 33 + i; if (g > 8191) g = 8191;
                            dst[i*128] = (f16)((const float*)data)[prow + g];
                        }
                    }
                }
            }

            // ---- B fragments
            const f16* hxc = hxread0 + cur*HXBUF;
            half8 bfr[8];
            #pragma unroll
            for (int q = 0; q < 7; ++q) bfr[q] = *(const half8*)(hxc + q*32);
            {
                const f16* b7;
                if (quad < 2)       b7 = hxc + 7*32;
                else if (quad == 2) b7 = &dwin[(t>>5)&1][t&31][n16][0];
                else                b7 = zrow;
                half8 bb = *(const half8*)b7;
                if (quad == 3) bb[0] = pb1h;
                bfr[7] = bb;
            }

            // ---- GEMM: 2 independent 8-deep chains
            f32x4 acc[2];
            #pragma unroll
            for (int i = 0; i < 2; ++i) { f32x4 z = {0.f,0.f,0.f,0.f}; acc[i] = z; }
            #pragma unroll
            for (int q = 0; q < 8; ++q) {
                #pragma unroll
                for (int i = 0; i < 2; ++i)
                    acc[i] = __builtin_amdgcn_mfma_f32_16x16x32_f16(af[i][q], bfr[q], acc[i], 0, 0, 0);
            }

            // ---- epilogue
            f16* hxn = hxw + nxt*HXBUF;
            #pragma unroll
            for (int i = 0; i < 2; ++i) {
                int rt = w*2 + i;
                if (rt < 15) {
                    half4v hv;
                    hv.x = (f16)fmaxf(acc[i].x, 0.f);
                    hv.y = (f16)fmaxf(acc[i].y, 0.f);
                    hv.z = (f16)fmaxf(acc[i].z, 0.f);
                    hv.w = (f16)fmaxf(acc[i].w, 0.f);
                    *(half4v*)(hxn + rt*16) = hv;
                } else if (bvalid) {             // rt==15 (wave 7): out rows, direct store
                    long ob = ((long)bn*T_STEPS + t)*6;
                    if (quad == 0) {
                        if (!f32) {
                            bf16* op = (bf16*)out + ob;
                            *(unsigned*)(op)     = pkbf(acc[i].x, acc[i].y);
                            *(unsigned*)(op + 2) = pkbf(acc[i].z, acc[i].w);
                        } else {
                            float* op = (float*)out + ob;
                            f32x2 p0 = {acc[i].x, acc[i].y}; *(f32x2*)(op)     = p0;
                            f32x2 p1 = {acc[i].z, acc[i].w}; *(f32x2*)(op + 2) = p1;
                        }
                    } else if (quad == 1) {
                        if (!f32) {
                            bf16* op = (bf16*)out + ob;
                            *(unsigned*)(op + 4) = pkbf(acc[i].x, acc[i].y);
                        } else {
                            float* op = (float*)out + ob;
                            f32x2 p0 = {acc[i].x, acc[i].y}; *(f32x2*)(op + 4) = p0;
                        }
                    }
                }
            }
            barrier_lds();                       // lgkmcnt only -- vmem stays in flight
        }
    }
}

extern "C" void kernel_launch(void* const* d_in, const int* in_sizes, int n_in,
                              void* d_out, int out_size, void* d_ws, size_t ws_size,
                              hipStream_t stream) {
    const void* data = d_in[0];
    const void* W1d  = d_in[1];
    const void* b1d  = d_in[2];
    const void* W1p  = d_in[3];
    const void* b1p  = d_in[4];
    const void* W1c  = d_in[5];
    const void* b1c  = d_in[6];
    const void* W2d  = d_in[7];
    const void* b2d  = d_in[8];
    const void* W2c  = d_in[9];
    const void* b2c  = d_in[10];
    const void* pb   = d_in[11];

    size_t need = SCRATCH_BYTES;
    char* scratch;
    if (ws_size >= need) {
        scratch = (char*)d_ws;
    } else {
        size_t out_bytes = (size_t)30*T_STEPS*6*sizeof(bf16);
        scratch = (char*)d_out + ((out_bytes - need) & ~(size_t)255);
    }
    f16* Aa    = (f16*)scratch;
    int* flagp = (int*)(scratch + A_HALVES*2);

    detect_dtype<<<1, 64, 0, stream>>>(data, flagp);
    build_A<<<A_HALVES/256, 256, 0, stream>>>(W1d, b1d, W1p, b1p, W1c, b1c,
                                              W2d, b2d, W2c, b2c, Aa, flagp);
    rnn_mfma<<<2, 512, 0, stream>>>(data, b1d, W1p, b1p, b1c, W1d, pb,
                                    Aa, flagp, d_out);
}